// Round 8
// baseline (95.277 us; speedup 1.0000x reference)
//
#include <hip/hip_runtime.h>

#define BLOCK 256
#define SENTINEL 0xAAAAAAAAu   // negative float (-3.03e-13); partial >= 0 can never equal it

// ---------------------------------------------------------------------------
// Kernel 1: per-face precompute + partial[] sentinel init.
//   cent[f]      = centroid (xyz)
//   g0[f] = (gv.xyz, cv):  v = dot(p,gv)+cv
//   g1[f] = (gw.xyz, cw):  w = dot(p,gw)+cw,  u = 1-v-w
//   spts[f*S+s]  = sample point s of face f
//   partial[f]   = sentinel (consumed by pair kernel's block-0 spin reduce)
// ---------------------------------------------------------------------------
__global__ void face_pre_kernel(const float* __restrict__ verts,
                                const int* __restrict__ faces,
                                const float* __restrict__ alpha,
                                const float* __restrict__ beta,
                                int F, int S,
                                float4* __restrict__ cent,
                                float4* __restrict__ g0,
                                float4* __restrict__ g1,
                                float4* __restrict__ spts,
                                float* __restrict__ partial) {
    int f = blockIdx.x * blockDim.x + threadIdx.x;
    if (f >= F) return;

    partial[f] = __uint_as_float(SENTINEL);   // ordered before pair (same stream)

    int i0 = faces[3 * f + 0];
    int i1 = faces[3 * f + 1];
    int i2 = faces[3 * f + 2];
    float ax = verts[3 * i0 + 0], ay = verts[3 * i0 + 1], az = verts[3 * i0 + 2];
    float bx = verts[3 * i1 + 0], by = verts[3 * i1 + 1], bz = verts[3 * i1 + 2];
    float cx = verts[3 * i2 + 0], cy = verts[3 * i2 + 1], cz = verts[3 * i2 + 2];

    float e0x = bx - ax, e0y = by - ay, e0z = bz - az;
    float e1x = cx - ax, e1y = cy - ay, e1z = cz - az;

    float d00 = e0x * e0x + e0y * e0y + e0z * e0z;
    float d01 = e0x * e1x + e0y * e1y + e0z * e1z;
    float d11 = e1x * e1x + e1y * e1y + e1z * e1z;
    float inv = 1.0f / (d00 * d11 - d01 * d01);
    float A = d11 * inv, B = d01 * inv, C = d00 * inv;

    float w1e0 = ax * e0x + ay * e0y + az * e0z;
    float w1e1 = ax * e1x + ay * e1y + az * e1z;

    const float third = 1.0f / 3.0f;
    cent[f] = make_float4((ax + bx + cx) * third,
                          (ay + by + cy) * third,
                          (az + bz + cz) * third, 0.0f);
    g0[f] = make_float4(A * e0x - B * e1x, A * e0y - B * e1y, A * e0z - B * e1z,
                        B * w1e1 - A * w1e0);
    g1[f] = make_float4(C * e1x - B * e0x, C * e1y - B * e0y, C * e1z - B * e0z,
                        B * w1e0 - C * w1e1);

    for (int s = 0; s < S; ++s) {
        float al = alpha[(long long)f * S + s];
        float be = beta[(long long)f * S + s];
        float ga = 1.0f - al - be;
        spts[(long long)f * S + s] =
            make_float4(al * ax + be * bx + ga * cx,
                        al * ay + be * by + ga * cy,
                        al * az + be * bz + ga * cz, 0.0f);
    }
}

// ---------------------------------------------------------------------------
// Kernel 2: pair kernel (compaction) + block-0 sentinel-spin final reduce.
// One block per i.
//   Phase 1: dist test over all F j's; survivors -> LDS queue
//            (ballot + mbcnt prefix + one ds-atomic per wave).
//   Phase 2: dense barycentric tests over the compacted queue.
//   Epilogue: block count -> partial[i] via agent-scope RELEASE store.
//   Block 0 then acquire-spin-loads every partial[f] until != sentinel,
//   sums, writes out[0]. No contended counters, no fences, no extra node.
// Deadlock-free: blocks are independent; block 0 merely occupies one slot
// while the scheduler cycles the rest.
// Dynamic LDS: F ints.
// ---------------------------------------------------------------------------
template <int SS>
__global__ void __launch_bounds__(BLOCK)
pair_kernel(const float4* __restrict__ cent,
            const float4* __restrict__ g0,
            const float4* __restrict__ g1,
            const float4* __restrict__ spts,
            const float* __restrict__ face_probs,
            int F,
            float* __restrict__ partial,
            float* __restrict__ out) {
    const int i = blockIdx.x;
    const int tid = threadIdx.x;
    const int lane = tid & 63;

    extern __shared__ int s_queue[];   // F ints
    __shared__ int s_n;
    __shared__ int wave_cnt[BLOCK / 64];
    if (tid == 0) s_n = 0;

    // ---- uniform prologue (scalar loads; i is block-uniform) ----
    const float4 ci = cent[i];
    float sx[SS], sy[SS], sz[SS];
#pragma unroll
    for (int s = 0; s < SS; ++s) {
        float4 p = spts[i * SS + s];
        sx[s] = p.x; sy[s] = p.y; sz[s] = p.z;
    }
    __syncthreads();

    // ---- phase 1: dist test + compaction into LDS queue ----
    for (int k = 0; k < F; k += BLOCK) {
        int j = k + tid;
        bool pass = false;
        if (j < F) {
            float4 c = cent[j];
            float dx = ci.x - c.x, dy = ci.y - c.y, dz = ci.z - c.z;
            float d2 = dx * dx + dy * dy + dz * dz;
            pass = (d2 < 1.0f) && (j != i);
        }
        unsigned long long m = __ballot(pass);
        int prefix = __builtin_amdgcn_mbcnt_hi((unsigned int)(m >> 32),
                     __builtin_amdgcn_mbcnt_lo((unsigned int)m, 0));
        int wtotal = __popcll(m);
        int base = 0;
        if (lane == 0 && wtotal) base = atomicAdd(&s_n, wtotal);
        base = __shfl(base, 0, 64);
        if (pass) s_queue[base + prefix] = j;
    }
    __syncthreads();
    const int n = s_n;

    // ---- phase 2: dense barycentric tests over compacted queue ----
    int count = 0;
    for (int k = tid; k < n; k += BLOCK) {
        int j = s_queue[k];
        float4 a = g0[j];
        float4 b = g1[j];
        float best = -1.0f;
#pragma unroll
        for (int s = 0; s < SS; ++s) {
            float vv = fmaf(sz[s], a.z, fmaf(sy[s], a.y, fmaf(sx[s], a.x, a.w)));
            float ww = fmaf(sz[s], b.z, fmaf(sy[s], b.y, fmaf(sx[s], b.x, b.w)));
            float uu = 1.0f - vv - ww;
            best = fmaxf(best, fminf(uu, fminf(vv, ww)));
        }
        count += (best >= 0.0f) ? 1 : 0;
    }

    // ---- block reduce -> release store of partial[i] ----
    for (int off = 32; off > 0; off >>= 1)
        count += __shfl_down(count, off, 64);
    if (lane == 0) wave_cnt[tid >> 6] = count;
    __syncthreads();
    if (tid == 0) {
        int tot = 0;
#pragma unroll
        for (int w = 0; w < BLOCK / 64; ++w) tot += wave_cnt[w];
        float p = face_probs[i] * (float)tot;      // p >= 0 always
        __hip_atomic_store(&partial[i], p, __ATOMIC_RELEASE,
                           __HIP_MEMORY_SCOPE_AGENT);
    }

    // ---- block 0: sentinel-spin final reduce ----
    if (i == 0) {
        float sum = 0.0f;
        for (int f = tid; f < F; f += BLOCK) {
            float v;
            do {
                v = __hip_atomic_load(&partial[f], __ATOMIC_ACQUIRE,
                                      __HIP_MEMORY_SCOPE_AGENT);
            } while (__float_as_uint(v) == SENTINEL);
            sum += v;
        }
        for (int off = 32; off > 0; off >>= 1)
            sum += __shfl_down(sum, off, 64);
        __shared__ float wave_sum[BLOCK / 64];
        if (lane == 0) wave_sum[tid >> 6] = sum;
        __syncthreads();
        if (tid == 0) {
            float tot = 0.0f;
#pragma unroll
            for (int w = 0; w < BLOCK / 64; ++w) tot += wave_sum[w];
            out[0] = tot / (float)F;
        }
    }
}

// ---------------------------------------------------------------------------
// Generic-S fallback: 3-kernel path (samples in LDS), used only if S != 10.
// ---------------------------------------------------------------------------
#define MAXS_G 64
__global__ void __launch_bounds__(BLOCK)
pair_kernel_generic(const float4* __restrict__ cent,
                    const float4* __restrict__ g0,
                    const float4* __restrict__ g1,
                    const float4* __restrict__ spts,
                    const float* __restrict__ face_probs,
                    int F, int S,
                    float* __restrict__ partial) {
    const int i = blockIdx.x;
    const int tid = threadIdx.x;
    __shared__ float s_x[MAXS_G], s_y[MAXS_G], s_z[MAXS_G];
    for (int s = tid; s < S; s += BLOCK) {
        float4 p = spts[(long long)i * S + s];
        s_x[s] = p.x; s_y[s] = p.y; s_z[s] = p.z;
    }
    __syncthreads();
    const float4 ci = cent[i];

    int count = 0;
    for (int j = tid; j < F; j += BLOCK) {
        float4 cj = cent[j];
        float dx = ci.x - cj.x, dy = ci.y - cj.y, dz = ci.z - cj.z;
        float d2 = dx * dx + dy * dy + dz * dz;
        if ((d2 < 1.0f) && (j != i)) {
            float4 a = g0[j];
            float4 b = g1[j];
            float best = -1.0f;
            for (int s = 0; s < S; ++s) {
                float vv = fmaf(s_z[s], a.z, fmaf(s_y[s], a.y, fmaf(s_x[s], a.x, a.w)));
                float ww = fmaf(s_z[s], b.z, fmaf(s_y[s], b.y, fmaf(s_x[s], b.x, b.w)));
                float uu = 1.0f - vv - ww;
                best = fmaxf(best, fminf(uu, fminf(vv, ww)));
            }
            count += (best >= 0.0f) ? 1 : 0;
        }
    }

    for (int off = 32; off > 0; off >>= 1)
        count += __shfl_down(count, off, 64);
    __shared__ int wave_cnt[BLOCK / 64];
    if ((tid & 63) == 0) wave_cnt[tid >> 6] = count;
    __syncthreads();
    if (tid == 0) {
        int tot = 0;
#pragma unroll
        for (int w = 0; w < BLOCK / 64; ++w) tot += wave_cnt[w];
        partial[i] = face_probs[i] * (float)tot;
    }
}

__global__ void __launch_bounds__(BLOCK)
reduce_kernel(const float* __restrict__ partial, float* __restrict__ out,
              int F, float invF) {
    const int tid = threadIdx.x;
    float sum = 0.0f;
    for (int f = tid; f < F; f += BLOCK) sum += partial[f];
    for (int off = 32; off > 0; off >>= 1)
        sum += __shfl_down(sum, off, 64);
    __shared__ float wave_sum[BLOCK / 64];
    if ((tid & 63) == 0) wave_sum[tid >> 6] = sum;
    __syncthreads();
    if (tid == 0) {
        float tot = 0.0f;
#pragma unroll
        for (int w = 0; w < BLOCK / 64; ++w) tot += wave_sum[w];
        out[0] = tot * invF;
    }
}

extern "C" void kernel_launch(void* const* d_in, const int* in_sizes, int n_in,
                              void* d_out, int out_size, void* d_ws, size_t ws_size,
                              hipStream_t stream) {
    const float* vertices   = (const float*)d_in[0];
    const int*   faces      = (const int*)d_in[1];
    const float* face_probs = (const float*)d_in[2];
    const float* alpha      = (const float*)d_in[3];
    const float* beta       = (const float*)d_in[4];
    float* out = (float*)d_out;

    const int F = in_sizes[2];
    const int S = in_sizes[3] / F;

    // Workspace: cent[F], g0[F], g1[F], spts[F*S] (float4), partial[F].
    char* ws = (char*)d_ws;
    float4* cent = (float4*)ws;
    float4* g0   = cent + F;
    float4* g1   = g0 + F;
    float4* spts = g1 + F;
    float*  partial = (float*)(spts + (long long)F * S);

    face_pre_kernel<<<(F + BLOCK - 1) / BLOCK, BLOCK, 0, stream>>>(
        vertices, faces, alpha, beta, F, S, cent, g0, g1, spts, partial);

    if (S == 10) {
        size_t lds = (size_t)F * sizeof(int);
        pair_kernel<10><<<F, BLOCK, lds, stream>>>(
            cent, g0, g1, spts, face_probs, F, partial, out);
    } else {
        pair_kernel_generic<<<F, BLOCK, 0, stream>>>(
            cent, g0, g1, spts, face_probs, F, S, partial);
        reduce_kernel<<<1, BLOCK, 0, stream>>>(partial, out, F, 1.0f / (float)F);
    }
}

// Round 9
// 94.023 us; speedup vs baseline: 1.0133x; 1.0133x over previous
//
#include <hip/hip_runtime.h>

#define BLOCK 256
#define SENTINEL 0xAAAAAAAAu   // negative float; partial >= 0 can never equal it

// ---------------------------------------------------------------------------
// Kernel 1: per-face precompute + partial[] sentinel init.
//   cent[f]      = centroid (xyz)
//   g0[f] = (gv.xyz, cv):  v = dot(p,gv)+cv
//   g1[f] = (gw.xyz, cw):  w = dot(p,gw)+cw,  u = 1-v-w
//   spts[f*S+s]  = sample point s of face f
//   partial[f]   = sentinel (consumed by pair kernel's last-block poll)
// ---------------------------------------------------------------------------
__global__ void face_pre_kernel(const float* __restrict__ verts,
                                const int* __restrict__ faces,
                                const float* __restrict__ alpha,
                                const float* __restrict__ beta,
                                int F, int S,
                                float4* __restrict__ cent,
                                float4* __restrict__ g0,
                                float4* __restrict__ g1,
                                float4* __restrict__ spts,
                                float* __restrict__ partial) {
    int f = blockIdx.x * blockDim.x + threadIdx.x;
    if (f >= F) return;

    partial[f] = __uint_as_float(SENTINEL);   // same-stream ordering before pair

    int i0 = faces[3 * f + 0];
    int i1 = faces[3 * f + 1];
    int i2 = faces[3 * f + 2];
    float ax = verts[3 * i0 + 0], ay = verts[3 * i0 + 1], az = verts[3 * i0 + 2];
    float bx = verts[3 * i1 + 0], by = verts[3 * i1 + 1], bz = verts[3 * i1 + 2];
    float cx = verts[3 * i2 + 0], cy = verts[3 * i2 + 1], cz = verts[3 * i2 + 2];

    float e0x = bx - ax, e0y = by - ay, e0z = bz - az;
    float e1x = cx - ax, e1y = cy - ay, e1z = cz - az;

    float d00 = e0x * e0x + e0y * e0y + e0z * e0z;
    float d01 = e0x * e1x + e0y * e1y + e0z * e1z;
    float d11 = e1x * e1x + e1y * e1y + e1z * e1z;
    float inv = 1.0f / (d00 * d11 - d01 * d01);
    float A = d11 * inv, B = d01 * inv, C = d00 * inv;

    float w1e0 = ax * e0x + ay * e0y + az * e0z;
    float w1e1 = ax * e1x + ay * e1y + az * e1z;

    const float third = 1.0f / 3.0f;
    cent[f] = make_float4((ax + bx + cx) * third,
                          (ay + by + cy) * third,
                          (az + bz + cz) * third, 0.0f);
    g0[f] = make_float4(A * e0x - B * e1x, A * e0y - B * e1y, A * e0z - B * e1z,
                        B * w1e1 - A * w1e0);
    g1[f] = make_float4(C * e1x - B * e0x, C * e1y - B * e0y, C * e1z - B * e0z,
                        B * w1e0 - C * w1e1);

    for (int s = 0; s < S; ++s) {
        float al = alpha[(long long)f * S + s];
        float be = beta[(long long)f * S + s];
        float ga = 1.0f - al - be;
        spts[(long long)f * S + s] =
            make_float4(al * ax + be * bx + ga * cx,
                        al * ay + be * by + ga * cy,
                        al * az + be * bz + ga * cz, 0.0f);
    }
}

// ---------------------------------------------------------------------------
// Kernel 2: pair kernel (compaction) + LAST-block relaxed-poll final reduce.
// One block per i (R6 body verbatim, incl. centroid prefetch).
// Epilogue: partial[i] release-stored; the LAST block (i==F-1, dispatched
// last, finishes last) polls all partials with RELAXED loads + s_sleep
// backoff (no acquire L1-invalidate storm, ~0 expected spin), then writes
// out[0]. Relaxed is sufficient: each partial is one aligned 32-bit word —
// a poll returns either the sentinel or the final value, never torn.
// All 2048 blocks co-resident (8/CU: 8.3KB LDS, 24 VGPR) -> no deadlock.
// Dynamic LDS: F ints.
// ---------------------------------------------------------------------------
template <int SS>
__global__ void __launch_bounds__(BLOCK)
pair_kernel(const float4* __restrict__ cent,
            const float4* __restrict__ g0,
            const float4* __restrict__ g1,
            const float4* __restrict__ spts,
            const float* __restrict__ face_probs,
            int F,
            float* __restrict__ partial,
            float* __restrict__ out) {
    const int i = blockIdx.x;
    const int tid = threadIdx.x;
    const int lane = tid & 63;

    extern __shared__ int s_queue[];   // F ints
    __shared__ int s_n;
    __shared__ int wave_cnt[BLOCK / 64];
    if (tid == 0) s_n = 0;

    // ---- uniform prologue (scalar loads; i is block-uniform) ----
    const float4 ci = cent[i];
    float sx[SS], sy[SS], sz[SS];
#pragma unroll
    for (int s = 0; s < SS; ++s) {
        float4 p = spts[i * SS + s];
        sx[s] = p.x; sy[s] = p.y; sz[s] = p.z;
    }
    __syncthreads();

    // ---- phase 1: dist test + compaction into LDS queue (prefetched) ----
    float4 c_next = (tid < F) ? cent[tid] : make_float4(1e30f, 1e30f, 1e30f, 0.f);
    for (int k = 0; k < F; k += BLOCK) {
        int j = k + tid;
        float4 c = c_next;
        int jn = k + BLOCK + tid;
        if (jn < F) c_next = cent[jn];             // prefetch next iter
        float dx = ci.x - c.x, dy = ci.y - c.y, dz = ci.z - c.z;
        float d2 = dx * dx + dy * dy + dz * dz;
        bool pass = (j < F) && (d2 < 1.0f) && (j != i);
        unsigned long long m = __ballot(pass);
        int prefix = __builtin_amdgcn_mbcnt_hi((unsigned int)(m >> 32),
                     __builtin_amdgcn_mbcnt_lo((unsigned int)m, 0));
        int wtotal = __popcll(m);
        int base = 0;
        if (lane == 0 && wtotal) base = atomicAdd(&s_n, wtotal);
        base = __shfl(base, 0, 64);
        if (pass) s_queue[base + prefix] = j;
    }
    __syncthreads();
    const int n = s_n;

    // ---- phase 2: dense barycentric tests over compacted queue ----
    int count = 0;
    for (int k = tid; k < n; k += BLOCK) {
        int j = s_queue[k];
        float4 a = g0[j];
        float4 b = g1[j];
        float best = -1.0f;
#pragma unroll
        for (int s = 0; s < SS; ++s) {
            float vv = fmaf(sz[s], a.z, fmaf(sy[s], a.y, fmaf(sx[s], a.x, a.w)));
            float ww = fmaf(sz[s], b.z, fmaf(sy[s], b.y, fmaf(sx[s], b.x, b.w)));
            float uu = 1.0f - vv - ww;
            best = fmaxf(best, fminf(uu, fminf(vv, ww)));
        }
        count += (best >= 0.0f) ? 1 : 0;
    }

    // ---- block reduce -> release store of partial[i] ----
    for (int off = 32; off > 0; off >>= 1)
        count += __shfl_down(count, off, 64);
    if (lane == 0) wave_cnt[tid >> 6] = count;
    __syncthreads();
    if (tid == 0) {
        int tot = 0;
#pragma unroll
        for (int w = 0; w < BLOCK / 64; ++w) tot += wave_cnt[w];
        float p = face_probs[i] * (float)tot;      // p >= 0 always
        __hip_atomic_store(&partial[i], p, __ATOMIC_RELEASE,
                           __HIP_MEMORY_SCOPE_AGENT);
    }

    // ---- LAST block: relaxed-poll + backoff final reduce ----
    if (i == F - 1) {
        bool done = false;
        while (!done) {
            bool mine = true;
            for (int f = tid; f < F; f += BLOCK) {
                float v = __hip_atomic_load(&partial[f], __ATOMIC_RELAXED,
                                            __HIP_MEMORY_SCOPE_AGENT);
                if (__float_as_uint(v) == SENTINEL) { mine = false; break; }
            }
            done = __syncthreads_and(mine);
            if (!done) __builtin_amdgcn_s_sleep(16);   // ~1K cyc backoff
        }
        float sum = 0.0f;
        for (int f = tid; f < F; f += BLOCK)
            sum += __hip_atomic_load(&partial[f], __ATOMIC_RELAXED,
                                     __HIP_MEMORY_SCOPE_AGENT);
        for (int off = 32; off > 0; off >>= 1)
            sum += __shfl_down(sum, off, 64);
        __shared__ float wave_sum[BLOCK / 64];
        if (lane == 0) wave_sum[tid >> 6] = sum;
        __syncthreads();
        if (tid == 0) {
            float tot = 0.0f;
#pragma unroll
            for (int w = 0; w < BLOCK / 64; ++w) tot += wave_sum[w];
            out[0] = tot / (float)F;
        }
    }
}

// ---------------------------------------------------------------------------
// Generic-S fallback: 3-kernel path (samples in LDS), used only if S != 10.
// ---------------------------------------------------------------------------
#define MAXS_G 64
__global__ void __launch_bounds__(BLOCK)
pair_kernel_generic(const float4* __restrict__ cent,
                    const float4* __restrict__ g0,
                    const float4* __restrict__ g1,
                    const float4* __restrict__ spts,
                    const float* __restrict__ face_probs,
                    int F, int S,
                    float* __restrict__ partial) {
    const int i = blockIdx.x;
    const int tid = threadIdx.x;
    __shared__ float s_x[MAXS_G], s_y[MAXS_G], s_z[MAXS_G];
    for (int s = tid; s < S; s += BLOCK) {
        float4 p = spts[(long long)i * S + s];
        s_x[s] = p.x; s_y[s] = p.y; s_z[s] = p.z;
    }
    __syncthreads();
    const float4 ci = cent[i];

    int count = 0;
    for (int j = tid; j < F; j += BLOCK) {
        float4 cj = cent[j];
        float dx = ci.x - cj.x, dy = ci.y - cj.y, dz = ci.z - cj.z;
        float d2 = dx * dx + dy * dy + dz * dz;
        if ((d2 < 1.0f) && (j != i)) {
            float4 a = g0[j];
            float4 b = g1[j];
            float best = -1.0f;
            for (int s = 0; s < S; ++s) {
                float vv = fmaf(s_z[s], a.z, fmaf(s_y[s], a.y, fmaf(s_x[s], a.x, a.w)));
                float ww = fmaf(s_z[s], b.z, fmaf(s_y[s], b.y, fmaf(s_x[s], b.x, b.w)));
                float uu = 1.0f - vv - ww;
                best = fmaxf(best, fminf(uu, fminf(vv, ww)));
            }
            count += (best >= 0.0f) ? 1 : 0;
        }
    }

    for (int off = 32; off > 0; off >>= 1)
        count += __shfl_down(count, off, 64);
    __shared__ int wave_cnt[BLOCK / 64];
    if ((tid & 63) == 0) wave_cnt[tid >> 6] = count;
    __syncthreads();
    if (tid == 0) {
        int tot = 0;
#pragma unroll
        for (int w = 0; w < BLOCK / 64; ++w) tot += wave_cnt[w];
        partial[i] = face_probs[i] * (float)tot;
    }
}

__global__ void __launch_bounds__(BLOCK)
reduce_kernel(const float* __restrict__ partial, float* __restrict__ out,
              int F, float invF) {
    const int tid = threadIdx.x;
    float sum = 0.0f;
    for (int f = tid; f < F; f += BLOCK) sum += partial[f];
    for (int off = 32; off > 0; off >>= 1)
        sum += __shfl_down(sum, off, 64);
    __shared__ float wave_sum[BLOCK / 64];
    if ((tid & 63) == 0) wave_sum[tid >> 6] = sum;
    __syncthreads();
    if (tid == 0) {
        float tot = 0.0f;
#pragma unroll
        for (int w = 0; w < BLOCK / 64; ++w) tot += wave_sum[w];
        out[0] = tot * invF;
    }
}

extern "C" void kernel_launch(void* const* d_in, const int* in_sizes, int n_in,
                              void* d_out, int out_size, void* d_ws, size_t ws_size,
                              hipStream_t stream) {
    const float* vertices   = (const float*)d_in[0];
    const int*   faces      = (const int*)d_in[1];
    const float* face_probs = (const float*)d_in[2];
    const float* alpha      = (const float*)d_in[3];
    const float* beta       = (const float*)d_in[4];
    float* out = (float*)d_out;

    const int F = in_sizes[2];
    const int S = in_sizes[3] / F;

    // Workspace: cent[F], g0[F], g1[F], spts[F*S] (float4), partial[F].
    char* ws = (char*)d_ws;
    float4* cent = (float4*)ws;
    float4* g0   = cent + F;
    float4* g1   = g0 + F;
    float4* spts = g1 + F;
    float*  partial = (float*)(spts + (long long)F * S);

    face_pre_kernel<<<(F + BLOCK - 1) / BLOCK, BLOCK, 0, stream>>>(
        vertices, faces, alpha, beta, F, S, cent, g0, g1, spts, partial);

    if (S == 10) {
        size_t lds = (size_t)F * sizeof(int);
        pair_kernel<10><<<F, BLOCK, lds, stream>>>(
            cent, g0, g1, spts, face_probs, F, partial, out);
    } else {
        pair_kernel_generic<<<F, BLOCK, 0, stream>>>(
            cent, g0, g1, spts, face_probs, F, S, partial);
        reduce_kernel<<<1, BLOCK, 0, stream>>>(partial, out, F, 1.0f / (float)F);
    }
}

// Round 10
// 75.871 us; speedup vs baseline: 1.2558x; 1.2392x over previous
//
#include <hip/hip_runtime.h>

#define BLOCK 256

// ---------------------------------------------------------------------------
// Kernel 1: per-face precompute, one thread per (f,s) pair (wide launch).
//   cent[f]      = centroid (xyz)
//   g0[f] = (gv.xyz, cv):  v = dot(p,gv)+cv
//   g1[f] = (gw.xyz, cw):  w = dot(p,gw)+cw,  u = 1-v-w
//   spts[f*S+s]  = sample point s of face f
// Thread (f,s) computes spts[f*S+s]; the s==0 thread also writes the tables.
// Vertex gathers are redundant x S but all L1/L2 hits; latency now overlapped
// across F*S threads instead of serialized in a 10-iter loop on F threads.
// ---------------------------------------------------------------------------
__global__ void face_pre_kernel(const float* __restrict__ verts,
                                const int* __restrict__ faces,
                                const float* __restrict__ alpha,
                                const float* __restrict__ beta,
                                int F, int S,
                                float4* __restrict__ cent,
                                float4* __restrict__ g0,
                                float4* __restrict__ g1,
                                float4* __restrict__ spts) {
    int idx = blockIdx.x * blockDim.x + threadIdx.x;
    if (idx >= F * S) return;
    int f = idx / S;
    int s = idx - f * S;

    int i0 = faces[3 * f + 0];
    int i1 = faces[3 * f + 1];
    int i2 = faces[3 * f + 2];
    float ax = verts[3 * i0 + 0], ay = verts[3 * i0 + 1], az = verts[3 * i0 + 2];
    float bx = verts[3 * i1 + 0], by = verts[3 * i1 + 1], bz = verts[3 * i1 + 2];
    float cx = verts[3 * i2 + 0], cy = verts[3 * i2 + 1], cz = verts[3 * i2 + 2];

    float al = alpha[idx];
    float be = beta[idx];
    float ga = 1.0f - al - be;
    spts[idx] = make_float4(al * ax + be * bx + ga * cx,
                            al * ay + be * by + ga * cy,
                            al * az + be * bz + ga * cz, 0.0f);

    if (s == 0) {
        float e0x = bx - ax, e0y = by - ay, e0z = bz - az;
        float e1x = cx - ax, e1y = cy - ay, e1z = cz - az;

        float d00 = e0x * e0x + e0y * e0y + e0z * e0z;
        float d01 = e0x * e1x + e0y * e1y + e0z * e1z;
        float d11 = e1x * e1x + e1y * e1y + e1z * e1z;
        float inv = 1.0f / (d00 * d11 - d01 * d01);
        float A = d11 * inv, B = d01 * inv, C = d00 * inv;

        float w1e0 = ax * e0x + ay * e0y + az * e0z;
        float w1e1 = ax * e1x + ay * e1y + az * e1z;

        const float third = 1.0f / 3.0f;
        cent[f] = make_float4((ax + bx + cx) * third,
                              (ay + by + cy) * third,
                              (az + bz + cz) * third, 0.0f);
        g0[f] = make_float4(A * e0x - B * e1x, A * e0y - B * e1y,
                            A * e0z - B * e1z, B * w1e1 - A * w1e0);
        g1[f] = make_float4(C * e1x - B * e0x, C * e1y - B * e0y,
                            C * e1z - B * e0z, B * w1e0 - C * w1e1);
    }
}

// ---------------------------------------------------------------------------
// Kernel 2: pair kernel, wave-private compaction, barrier-free main body.
// One block per i.
//   Phase 1 (per wave): dist-test its own j's (lane stride within wave's
//     chunk), compact survivors into the wave's PRIVATE LDS segment.
//     Offset tracked in a register via popcll -- NO LDS atomics, NO shfl
//     broadcast, NO __syncthreads between phases.
//   Phase 2 (per wave): depth-2 software-pipelined walk of its own segment:
//     next queue entry + g0/g1 gathers issued before computing current.
//   Epilogue: single __syncthreads, cross-wave LDS reduce, one plain store.
// Dynamic LDS: 4 * SEG ints, SEG = ceil(F/BLOCK)*64.
// ---------------------------------------------------------------------------
template <int SS>
__global__ void __launch_bounds__(BLOCK)
pair_kernel(const float4* __restrict__ cent,
            const float4* __restrict__ g0,
            const float4* __restrict__ g1,
            const float4* __restrict__ spts,
            const float* __restrict__ face_probs,
            int F, int SEG,
            float* __restrict__ partial) {
    const int i = blockIdx.x;
    const int tid = threadIdx.x;
    const int lane = tid & 63;
    const int wave = tid >> 6;

    extern __shared__ int s_queue[];          // 4 * SEG ints
    __shared__ int wave_cnt[BLOCK / 64];
    const int wbase = wave * SEG;

    // ---- uniform prologue (scalar loads; i is block-uniform) ----
    const float4 ci = cent[i];
    float sx[SS], sy[SS], sz[SS];
#pragma unroll
    for (int s = 0; s < SS; ++s) {
        float4 p = spts[i * SS + s];
        sx[s] = p.x; sy[s] = p.y; sz[s] = p.z;
    }

    // ---- phase 1: wave-private dist test + compaction (no barriers) ----
    int wlen = 0;                              // uniform across the wave
    float4 c_next = (tid < F) ? cent[tid]
                              : make_float4(1e30f, 1e30f, 1e30f, 0.0f);
    for (int k = 0; k < F; k += BLOCK) {
        int j = k + tid;
        float4 c = c_next;
        int jn = k + BLOCK + tid;
        if (jn < F) c_next = cent[jn];         // prefetch next iter
        float dx = ci.x - c.x, dy = ci.y - c.y, dz = ci.z - c.z;
        float d2 = dx * dx + dy * dy + dz * dz;
        bool pass = (j < F) && (d2 < 1.0f) && (j != i);
        unsigned long long m = __ballot(pass);
        int prefix = __builtin_amdgcn_mbcnt_hi((unsigned int)(m >> 32),
                     __builtin_amdgcn_mbcnt_lo((unsigned int)m, 0));
        if (pass) s_queue[wbase + wlen + prefix] = j;
        wlen += __popcll(m);
    }

    // ---- phase 2: depth-2 pipelined walk of the wave's own segment ----
    int count = 0;
    const int nIter = (wlen + 63) >> 6;
    bool  v_cur = lane < wlen;
    int   j_cur = v_cur ? s_queue[wbase + lane] : 0;
    float4 a_cur, b_cur;
    if (v_cur) { a_cur = g0[j_cur]; b_cur = g1[j_cur]; }
    for (int t = 0; t < nIter; ++t) {
        // prefetch iteration t+1
        int   k_n = lane + (t + 1) * 64;
        bool  v_n = k_n < wlen;
        int   j_n = v_n ? s_queue[wbase + k_n] : 0;
        float4 a_n, b_n;
        if (v_n) { a_n = g0[j_n]; b_n = g1[j_n]; }
        // compute iteration t
        if (v_cur) {
            float best = -1.0f;
#pragma unroll
            for (int s = 0; s < SS; ++s) {
                float vv = fmaf(sz[s], a_cur.z,
                            fmaf(sy[s], a_cur.y, fmaf(sx[s], a_cur.x, a_cur.w)));
                float ww = fmaf(sz[s], b_cur.z,
                            fmaf(sy[s], b_cur.y, fmaf(sx[s], b_cur.x, b_cur.w)));
                float uu = 1.0f - vv - ww;
                best = fmaxf(best, fminf(uu, fminf(vv, ww)));
            }
            count += (best >= 0.0f) ? 1 : 0;
        }
        v_cur = v_n; a_cur = a_n; b_cur = b_n;
    }

    // ---- epilogue: wave shuffle reduce -> LDS -> one plain store ----
    for (int off = 32; off > 0; off >>= 1)
        count += __shfl_down(count, off, 64);
    if (lane == 0) wave_cnt[wave] = count;
    __syncthreads();
    if (tid == 0) {
        int tot = 0;
#pragma unroll
        for (int w = 0; w < BLOCK / 64; ++w) tot += wave_cnt[w];
        partial[i] = face_probs[i] * (float)tot;   // unique slot, no atomic
    }
}

// ---------------------------------------------------------------------------
// Generic-S fallback (samples in LDS), used only if S != 10.
// ---------------------------------------------------------------------------
#define MAXS_G 64
__global__ void __launch_bounds__(BLOCK)
pair_kernel_generic(const float4* __restrict__ cent,
                    const float4* __restrict__ g0,
                    const float4* __restrict__ g1,
                    const float4* __restrict__ spts,
                    const float* __restrict__ face_probs,
                    int F, int S,
                    float* __restrict__ partial) {
    const int i = blockIdx.x;
    const int tid = threadIdx.x;
    __shared__ float s_x[MAXS_G], s_y[MAXS_G], s_z[MAXS_G];
    for (int s = tid; s < S; s += BLOCK) {
        float4 p = spts[(long long)i * S + s];
        s_x[s] = p.x; s_y[s] = p.y; s_z[s] = p.z;
    }
    __syncthreads();
    const float4 ci = cent[i];

    int count = 0;
    for (int j = tid; j < F; j += BLOCK) {
        float4 cj = cent[j];
        float dx = ci.x - cj.x, dy = ci.y - cj.y, dz = ci.z - cj.z;
        float d2 = dx * dx + dy * dy + dz * dz;
        if ((d2 < 1.0f) && (j != i)) {
            float4 a = g0[j];
            float4 b = g1[j];
            float best = -1.0f;
            for (int s = 0; s < S; ++s) {
                float vv = fmaf(s_z[s], a.z, fmaf(s_y[s], a.y, fmaf(s_x[s], a.x, a.w)));
                float ww = fmaf(s_z[s], b.z, fmaf(s_y[s], b.y, fmaf(s_x[s], b.x, b.w)));
                float uu = 1.0f - vv - ww;
                best = fmaxf(best, fminf(uu, fminf(vv, ww)));
            }
            count += (best >= 0.0f) ? 1 : 0;
        }
    }

    for (int off = 32; off > 0; off >>= 1)
        count += __shfl_down(count, off, 64);
    __shared__ int wave_cnt[BLOCK / 64];
    if ((tid & 63) == 0) wave_cnt[tid >> 6] = count;
    __syncthreads();
    if (tid == 0) {
        int tot = 0;
#pragma unroll
        for (int w = 0; w < BLOCK / 64; ++w) tot += wave_cnt[w];
        partial[i] = face_probs[i] * (float)tot;
    }
}

// ---------------------------------------------------------------------------
// Kernel 3: reduce partial[0..F) -> out[0] = sum / F. Single block, float4.
// ---------------------------------------------------------------------------
__global__ void __launch_bounds__(BLOCK)
reduce_kernel(const float* __restrict__ partial, float* __restrict__ out,
              int F, float invF) {
    const int tid = threadIdx.x;
    float sum = 0.0f;
    int F4 = F >> 2;
    const float4* p4 = (const float4*)partial;
    for (int f = tid; f < F4; f += BLOCK) {
        float4 v = p4[f];
        sum += (v.x + v.y) + (v.z + v.w);
    }
    for (int f = (F4 << 2) + tid; f < F; f += BLOCK) sum += partial[f];
    for (int off = 32; off > 0; off >>= 1)
        sum += __shfl_down(sum, off, 64);
    __shared__ float wave_sum[BLOCK / 64];
    if ((tid & 63) == 0) wave_sum[tid >> 6] = sum;
    __syncthreads();
    if (tid == 0) {
        float tot = 0.0f;
#pragma unroll
        for (int w = 0; w < BLOCK / 64; ++w) tot += wave_sum[w];
        out[0] = tot * invF;
    }
}

extern "C" void kernel_launch(void* const* d_in, const int* in_sizes, int n_in,
                              void* d_out, int out_size, void* d_ws, size_t ws_size,
                              hipStream_t stream) {
    const float* vertices   = (const float*)d_in[0];
    const int*   faces      = (const int*)d_in[1];
    const float* face_probs = (const float*)d_in[2];
    const float* alpha      = (const float*)d_in[3];
    const float* beta       = (const float*)d_in[4];
    float* out = (float*)d_out;

    const int F = in_sizes[2];
    const int S = in_sizes[3] / F;

    // Workspace: cent[F], g0[F], g1[F], spts[F*S] (float4), partial[F].
    char* ws = (char*)d_ws;
    float4* cent = (float4*)ws;
    float4* g0   = cent + F;
    float4* g1   = g0 + F;
    float4* spts = g1 + F;
    float*  partial = (float*)(spts + (long long)F * S);

    int nfs = F * S;
    face_pre_kernel<<<(nfs + BLOCK - 1) / BLOCK, BLOCK, 0, stream>>>(
        vertices, faces, alpha, beta, F, S, cent, g0, g1, spts);

    if (S == 10) {
        int SEG = ((F + BLOCK - 1) / BLOCK) * 64;  // per-wave queue capacity
        size_t lds = (size_t)(4 * SEG) * sizeof(int);
        pair_kernel<10><<<F, BLOCK, lds, stream>>>(
            cent, g0, g1, spts, face_probs, F, SEG, partial);
    } else {
        pair_kernel_generic<<<F, BLOCK, 0, stream>>>(
            cent, g0, g1, spts, face_probs, F, S, partial);
    }

    reduce_kernel<<<1, BLOCK, 0, stream>>>(partial, out, F, 1.0f / (float)F);
}

// Round 11
// 75.003 us; speedup vs baseline: 1.2703x; 1.0116x over previous
//
#include <hip/hip_runtime.h>

#define BLOCK 256

__device__ __forceinline__ int mbcnt64(unsigned long long m) {
    return __builtin_amdgcn_mbcnt_hi((unsigned int)(m >> 32),
           __builtin_amdgcn_mbcnt_lo((unsigned int)m, 0));
}

// ---------------------------------------------------------------------------
// Kernel 1: per-face precompute, one thread per (f,s) (wide launch).
//   cent[f]       = centroid (xyz)
//   gg[2f+0] = (gv.xyz, cv):  v = dot(p,gv)+cv      } interleaved: both
//   gg[2f+1] = (gw.xyz, cw):  w = dot(p,gw)+cw      } fragments in one line
//   spts[f*S+s]   = sample point s of face f
// ---------------------------------------------------------------------------
__global__ void face_pre_kernel(const float* __restrict__ verts,
                                const int* __restrict__ faces,
                                const float* __restrict__ alpha,
                                const float* __restrict__ beta,
                                int F, int S,
                                float4* __restrict__ cent,
                                float4* __restrict__ gg,
                                float4* __restrict__ spts) {
    int idx = blockIdx.x * blockDim.x + threadIdx.x;
    if (idx >= F * S) return;
    int f = idx / S;
    int s = idx - f * S;

    int i0 = faces[3 * f + 0];
    int i1 = faces[3 * f + 1];
    int i2 = faces[3 * f + 2];
    float ax = verts[3 * i0 + 0], ay = verts[3 * i0 + 1], az = verts[3 * i0 + 2];
    float bx = verts[3 * i1 + 0], by = verts[3 * i1 + 1], bz = verts[3 * i1 + 2];
    float cx = verts[3 * i2 + 0], cy = verts[3 * i2 + 1], cz = verts[3 * i2 + 2];

    float al = alpha[idx];
    float be = beta[idx];
    float ga = 1.0f - al - be;
    spts[idx] = make_float4(al * ax + be * bx + ga * cx,
                            al * ay + be * by + ga * cy,
                            al * az + be * bz + ga * cz, 0.0f);

    if (s == 0) {
        float e0x = bx - ax, e0y = by - ay, e0z = bz - az;
        float e1x = cx - ax, e1y = cy - ay, e1z = cz - az;

        float d00 = e0x * e0x + e0y * e0y + e0z * e0z;
        float d01 = e0x * e1x + e0y * e1y + e0z * e1z;
        float d11 = e1x * e1x + e1y * e1y + e1z * e1z;
        float inv = 1.0f / (d00 * d11 - d01 * d01);
        float A = d11 * inv, B = d01 * inv, C = d00 * inv;

        float w1e0 = ax * e0x + ay * e0y + az * e0z;
        float w1e1 = ax * e1x + ay * e1y + az * e1z;

        const float third = 1.0f / 3.0f;
        cent[f] = make_float4((ax + bx + cx) * third,
                              (ay + by + cy) * third,
                              (az + bz + cz) * third, 0.0f);
        gg[2 * f + 0] = make_float4(A * e0x - B * e1x, A * e0y - B * e1y,
                                    A * e0z - B * e1z, B * w1e1 - A * w1e0);
        gg[2 * f + 1] = make_float4(C * e1x - B * e0x, C * e1y - B * e0y,
                                    C * e1z - B * e0z, B * w1e0 - C * w1e1);
    }
}

// ---------------------------------------------------------------------------
// Depth-2 pipelined walk of one wave-private queue segment.
// ---------------------------------------------------------------------------
template <int SS>
__device__ __forceinline__ int walk_queue(const int* s_queue, int wbase, int wlen,
                                          int lane,
                                          const float4* __restrict__ gg,
                                          const float* sx, const float* sy,
                                          const float* sz) {
    int count = 0;
    const int nIter = (wlen + 63) >> 6;
    bool  v_cur = lane < wlen;
    int   j_cur = v_cur ? s_queue[wbase + lane] : 0;
    float4 a_cur, b_cur;
    if (v_cur) { a_cur = gg[2 * j_cur]; b_cur = gg[2 * j_cur + 1]; }
    for (int t = 0; t < nIter; ++t) {
        int   k_n = lane + (t + 1) * 64;
        bool  v_n = k_n < wlen;
        int   j_n = v_n ? s_queue[wbase + k_n] : 0;
        float4 a_n, b_n;
        if (v_n) { a_n = gg[2 * j_n]; b_n = gg[2 * j_n + 1]; }
        if (v_cur) {
            float best = -1.0f;
#pragma unroll
            for (int s = 0; s < SS; ++s) {
                float vv = fmaf(sz[s], a_cur.z,
                            fmaf(sy[s], a_cur.y, fmaf(sx[s], a_cur.x, a_cur.w)));
                float ww = fmaf(sz[s], b_cur.z,
                            fmaf(sy[s], b_cur.y, fmaf(sx[s], b_cur.x, b_cur.w)));
                float uu = 1.0f - vv - ww;
                best = fmaxf(best, fminf(uu, fminf(vv, ww)));
            }
            count += (best >= 0.0f) ? 1 : 0;
        }
        v_cur = v_n; a_cur = a_n; b_cur = b_n;
    }
    return count;
}

// ---------------------------------------------------------------------------
// Kernel 2: pair kernel, TWO i's per block, wave-private compaction,
// barrier-free main body, interleaved gg gathers.
//   Phase 1: one cent stream tested against BOTH centroids (load cost
//            amortized 2x; global cent traffic halved vs R10).
//   Phase 2: two pipelined queue walks (one per i).
// Dynamic LDS: 8 * SEG ints (4 waves x 2 queues).
// ---------------------------------------------------------------------------
template <int SS>
__global__ void __launch_bounds__(BLOCK)
pair_kernel(const float4* __restrict__ cent,
            const float4* __restrict__ gg,
            const float4* __restrict__ spts,
            const float* __restrict__ face_probs,
            int F, int SEG,
            float* __restrict__ partial) {
    const int iA = blockIdx.x * 2;
    const int iB = iA + 1;
    const bool hasB = (iB < F);
    const int iBs = hasB ? iB : iA;          // safe index for loads
    const int tid = threadIdx.x;
    const int lane = tid & 63;
    const int wave = tid >> 6;

    extern __shared__ int s_queue[];          // 8 * SEG ints
    __shared__ int wave_cnt[2][BLOCK / 64];
    const int wbaseA = wave * SEG;
    const int wbaseB = (4 + wave) * SEG;

    // ---- uniform prologue (scalar loads; iA/iB block-uniform) ----
    const float4 ciA = cent[iA];
    const float4 ciB = cent[iBs];
    float sxA[SS], syA[SS], szA[SS], sxB[SS], syB[SS], szB[SS];
#pragma unroll
    for (int s = 0; s < SS; ++s) {
        float4 p = spts[iA * SS + s];
        sxA[s] = p.x; syA[s] = p.y; szA[s] = p.z;
        float4 q = spts[iBs * SS + s];
        sxB[s] = q.x; syB[s] = q.y; szB[s] = q.z;
    }

    // ---- phase 1: one cent stream, two dist tests, two private queues ----
    int wlenA = 0, wlenB = 0;
    float4 c_next = (tid < F) ? cent[tid]
                              : make_float4(1e30f, 1e30f, 1e30f, 0.0f);
    for (int k = 0; k < F; k += BLOCK) {
        int j = k + tid;
        float4 c = c_next;
        int jn = k + BLOCK + tid;
        if (jn < F) c_next = cent[jn];         // prefetch next iter
        float dxA = ciA.x - c.x, dyA = ciA.y - c.y, dzA = ciA.z - c.z;
        float d2A = dxA * dxA + dyA * dyA + dzA * dzA;
        bool passA = (j < F) && (d2A < 1.0f) && (j != iA);
        float dxB = ciB.x - c.x, dyB = ciB.y - c.y, dzB = ciB.z - c.z;
        float d2B = dxB * dxB + dyB * dyB + dzB * dzB;
        bool passB = hasB && (j < F) && (d2B < 1.0f) && (j != iB);

        unsigned long long mA = __ballot(passA);
        if (passA) s_queue[wbaseA + wlenA + mbcnt64(mA)] = j;
        wlenA += __popcll(mA);
        unsigned long long mB = __ballot(passB);
        if (passB) s_queue[wbaseB + wlenB + mbcnt64(mB)] = j;
        wlenB += __popcll(mB);
    }

    // ---- phase 2: pipelined walks ----
    int countA = walk_queue<SS>(s_queue, wbaseA, wlenA, lane, gg, sxA, syA, szA);
    int countB = walk_queue<SS>(s_queue, wbaseB, wlenB, lane, gg, sxB, syB, szB);

    // ---- epilogue: shuffle reduce both counts -> LDS -> two stores ----
    for (int off = 32; off > 0; off >>= 1) {
        countA += __shfl_down(countA, off, 64);
        countB += __shfl_down(countB, off, 64);
    }
    if (lane == 0) { wave_cnt[0][wave] = countA; wave_cnt[1][wave] = countB; }
    __syncthreads();
    if (tid == 0) {
        int tA = 0, tB = 0;
#pragma unroll
        for (int w = 0; w < BLOCK / 64; ++w) { tA += wave_cnt[0][w]; tB += wave_cnt[1][w]; }
        partial[iA] = face_probs[iA] * (float)tA;
        if (hasB) partial[iB] = face_probs[iB] * (float)tB;
    }
}

// ---------------------------------------------------------------------------
// Generic-S fallback (samples in LDS), used only if S != 10.
// ---------------------------------------------------------------------------
#define MAXS_G 64
__global__ void __launch_bounds__(BLOCK)
pair_kernel_generic(const float4* __restrict__ cent,
                    const float4* __restrict__ gg,
                    const float4* __restrict__ spts,
                    const float* __restrict__ face_probs,
                    int F, int S,
                    float* __restrict__ partial) {
    const int i = blockIdx.x;
    const int tid = threadIdx.x;
    __shared__ float s_x[MAXS_G], s_y[MAXS_G], s_z[MAXS_G];
    for (int s = tid; s < S; s += BLOCK) {
        float4 p = spts[(long long)i * S + s];
        s_x[s] = p.x; s_y[s] = p.y; s_z[s] = p.z;
    }
    __syncthreads();
    const float4 ci = cent[i];

    int count = 0;
    for (int j = tid; j < F; j += BLOCK) {
        float4 cj = cent[j];
        float dx = ci.x - cj.x, dy = ci.y - cj.y, dz = ci.z - cj.z;
        float d2 = dx * dx + dy * dy + dz * dz;
        if ((d2 < 1.0f) && (j != i)) {
            float4 a = gg[2 * j];
            float4 b = gg[2 * j + 1];
            float best = -1.0f;
            for (int s = 0; s < S; ++s) {
                float vv = fmaf(s_z[s], a.z, fmaf(s_y[s], a.y, fmaf(s_x[s], a.x, a.w)));
                float ww = fmaf(s_z[s], b.z, fmaf(s_y[s], b.y, fmaf(s_x[s], b.x, b.w)));
                float uu = 1.0f - vv - ww;
                best = fmaxf(best, fminf(uu, fminf(vv, ww)));
            }
            count += (best >= 0.0f) ? 1 : 0;
        }
    }

    for (int off = 32; off > 0; off >>= 1)
        count += __shfl_down(count, off, 64);
    __shared__ int wave_cnt[BLOCK / 64];
    if ((tid & 63) == 0) wave_cnt[tid >> 6] = count;
    __syncthreads();
    if (tid == 0) {
        int tot = 0;
#pragma unroll
        for (int w = 0; w < BLOCK / 64; ++w) tot += wave_cnt[w];
        partial[i] = face_probs[i] * (float)tot;
    }
}

// ---------------------------------------------------------------------------
// Kernel 3: reduce partial[0..F) -> out[0] = sum / F. Single block, float4.
// ---------------------------------------------------------------------------
__global__ void __launch_bounds__(BLOCK)
reduce_kernel(const float* __restrict__ partial, float* __restrict__ out,
              int F, float invF) {
    const int tid = threadIdx.x;
    float sum = 0.0f;
    int F4 = F >> 2;
    const float4* p4 = (const float4*)partial;
    for (int f = tid; f < F4; f += BLOCK) {
        float4 v = p4[f];
        sum += (v.x + v.y) + (v.z + v.w);
    }
    for (int f = (F4 << 2) + tid; f < F; f += BLOCK) sum += partial[f];
    for (int off = 32; off > 0; off >>= 1)
        sum += __shfl_down(sum, off, 64);
    __shared__ float wave_sum[BLOCK / 64];
    if ((tid & 63) == 0) wave_sum[tid >> 6] = sum;
    __syncthreads();
    if (tid == 0) {
        float tot = 0.0f;
#pragma unroll
        for (int w = 0; w < BLOCK / 64; ++w) tot += wave_sum[w];
        out[0] = tot * invF;
    }
}

extern "C" void kernel_launch(void* const* d_in, const int* in_sizes, int n_in,
                              void* d_out, int out_size, void* d_ws, size_t ws_size,
                              hipStream_t stream) {
    const float* vertices   = (const float*)d_in[0];
    const int*   faces      = (const int*)d_in[1];
    const float* face_probs = (const float*)d_in[2];
    const float* alpha      = (const float*)d_in[3];
    const float* beta       = (const float*)d_in[4];
    float* out = (float*)d_out;

    const int F = in_sizes[2];
    const int S = in_sizes[3] / F;

    // Workspace: cent[F], gg[2F], spts[F*S] (float4), partial[F].
    char* ws = (char*)d_ws;
    float4* cent = (float4*)ws;
    float4* gg   = cent + F;
    float4* spts = gg + 2 * F;
    float*  partial = (float*)(spts + (long long)F * S);

    int nfs = F * S;
    face_pre_kernel<<<(nfs + BLOCK - 1) / BLOCK, BLOCK, 0, stream>>>(
        vertices, faces, alpha, beta, F, S, cent, gg, spts);

    if (S == 10) {
        int SEG = ((F + BLOCK - 1) / BLOCK) * 64;  // per-wave queue capacity
        size_t lds = (size_t)(8 * SEG) * sizeof(int);
        int nblk = (F + 1) / 2;
        pair_kernel<10><<<nblk, BLOCK, lds, stream>>>(
            cent, gg, spts, face_probs, F, SEG, partial);
    } else {
        pair_kernel_generic<<<F, BLOCK, 0, stream>>>(
            cent, gg, spts, face_probs, F, S, partial);
    }

    reduce_kernel<<<1, BLOCK, 0, stream>>>(partial, out, F, 1.0f / (float)F);
}